// Round 19
// baseline (468.762 us; speedup 1.0000x reference)
//
#include <hip/hip_runtime.h>
#include <hip/hip_bf16.h>

using bf16 = __hip_bfloat16;

__device__ __forceinline__ float b2f(bf16 v) { return __bfloat162float(v); }
__device__ __forceinline__ bf16 f2b(float f) { return __float2bfloat16(f); }
__device__ __forceinline__ float u2f(unsigned short u) {
    return __uint_as_float(((unsigned)u) << 16);
}
// unpack a 32-bit word holding two bf16 (little-endian) to two floats
__device__ __forceinline__ void unpk(unsigned int w, float& a, float& b) {
    a = __uint_as_float(w << 16);
    b = __uint_as_float(w & 0xffff0000u);
}

#define B 8
#define CIN 256
#define HW 4096
#define QKV_CH 768
#define PROJ_IN 512
#define PROJ_OUT 256
#define NPG 2

// K0a: transpose w_qkv (768x256) -> wT (256x768). grid (3, 256).
__global__ __launch_bounds__(256) void k_wt(const float* __restrict__ w,
                                            float* __restrict__ wT) {
    int o = blockIdx.x * 256 + threadIdx.x;
    int c = blockIdx.y;
    wT[(size_t)c * QKV_CH + o] = w[(size_t)o * CIN + c];
}

// K0b: transpose w_proj (256x512) -> wT2 (512x256). grid (1, 512).
__global__ __launch_bounds__(256) void k_wt2(const float* __restrict__ w,
                                             float* __restrict__ wT2) {
    int o = threadIdx.x;
    int c = blockIdx.y;
    wT2[(size_t)c * PROJ_OUT + o] = w[(size_t)o * PROJ_IN + c];
}

// K1: qkv = w_qkv(768x256) @ x(b,256,4096) -> bf16, SCALAR-WEIGHT form.
// VERIFIED r17/r18: ~160us, LDS=0, VGPR 40, Occ 44%. block 256 = 2 o-groups
// x 128 p-threads; micro 16o x 4p; weights via wave-uniform s_load from wT.
// r19 change: unroll 4 -> 8 (8 in-flight float4 x-loads; VGPR headroom now
// exists at 40 regs -- round-13's prefetch failure was in the VGPR-68 LDS
// regime, not this one). Accumulation order per output unchanged.
// (Falsified levers, do NOT reapply: r12 chunked staging, r13 MANUAL
// prefetch, r14 512-thread blocks.)
__global__ __launch_bounds__(256) void k_qkv(const float* __restrict__ x,
                                             const float* __restrict__ wT,
                                             bf16* __restrict__ qkv) {
    int tid = threadIdx.x;
    int tp = tid & 127;
    int pg = blockIdx.x, og = blockIdx.y, b = blockIdx.z;

    int wuni = __builtin_amdgcn_readfirstlane(og * 32 + (tid >> 7) * 16);
    const float* wb = wT + wuni;

    float acc[16][4];
#pragma unroll
    for (int j = 0; j < 16; ++j)
#pragma unroll
        for (int i = 0; i < 4; ++i) acc[j][i] = 0.f;

    const float* xp = x + (size_t)b * CIN * HW + pg * 512 + tp * 4;
#pragma unroll 8
    for (int c = 0; c < 256; ++c) {
        float4 xv = *(const float4*)(xp + (size_t)c * HW);
        const float* wr = wb + (size_t)c * QKV_CH;
        float4 w0 = *(const float4*)(wr);
        float4 w1 = *(const float4*)(wr + 4);
        float4 w2 = *(const float4*)(wr + 8);
        float4 w3 = *(const float4*)(wr + 12);
        float xs[4] = {xv.x, xv.y, xv.z, xv.w};
        float ws[16] = {w0.x, w0.y, w0.z, w0.w, w1.x, w1.y, w1.z, w1.w,
                        w2.x, w2.y, w2.z, w2.w, w3.x, w3.y, w3.z, w3.w};
#pragma unroll
        for (int j = 0; j < 16; ++j)
#pragma unroll
            for (int i = 0; i < 4; ++i) acc[j][i] += ws[j] * xs[i];
    }

    int o0 = og * 32 + (tid >> 7) * 16;
#pragma unroll
    for (int j = 0; j < 16; ++j) {
        int o = o0 + j;
        union { bf16 h[4]; uint2 v; } pk;
#pragma unroll
        for (int i = 0; i < 4; ++i) pk.h[i] = f2b(acc[j][i]);
        *(uint2*)(qkv + ((size_t)b * QKV_CH + o) * HW + pg * 512 + tp * 4) = pk.v;
    }
}

// K2+K3 fused: depthwise 5x5 (pad 2) + group 8->8 pointwise mix. grid (2, 96, B)
__global__ __launch_bounds__(256) void k_dwagg(const bf16* __restrict__ qkv,
                                               const float* __restrict__ wdw,
                                               const float* __restrict__ wpw,
                                               bf16* __restrict__ dw) {
    int tid = threadIdx.x;
    int g = blockIdx.y, b = blockIdx.z;
    int x0 = (tid & 7) * 8;
    int y  = blockIdx.x * 32 + (tid >> 3);

    __shared__ float sdw[200];
    __shared__ float spw[64];
    if (tid < 200) sdw[tid] = wdw[(size_t)g * 200 + tid];
    if (tid < 64)  spw[tid] = wpw[(size_t)g * 64 + tid];
    __syncthreads();

    const bf16* src0 = qkv + ((size_t)b * QKV_CH + g * 8) * HW;

    float acc[8][8];
#pragma unroll
    for (int oc = 0; oc < 8; ++oc)
#pragma unroll
        for (int px = 0; px < 8; ++px) acc[oc][px] = 0.f;

#pragma unroll
    for (int c = 0; c < 8; ++c) {
        const bf16* src = src0 + (size_t)c * HW;
        float d[8];
#pragma unroll
        for (int px = 0; px < 8; ++px) d[px] = 0.f;

#pragma unroll
        for (int ky = 0; ky < 5; ++ky) {
            int yy = y + ky - 2;
            if (yy < 0 || yy > 63) continue;
            const bf16* row = src + yy * 64;
            float f[16];
            if (x0 > 0) {
                uint2 u = *(const uint2*)(row + x0 - 4);
                unpk(u.x, f[0], f[1]); unpk(u.y, f[2], f[3]);
            } else {
                f[0] = f[1] = f[2] = f[3] = 0.f;
            }
            uint4 m = *(const uint4*)(row + x0);
            unpk(m.x, f[4], f[5]);  unpk(m.y, f[6], f[7]);
            unpk(m.z, f[8], f[9]);  unpk(m.w, f[10], f[11]);
            if (x0 < 56) {
                uint2 u = *(const uint2*)(row + x0 + 8);
                unpk(u.x, f[12], f[13]); unpk(u.y, f[14], f[15]);
            } else {
                f[12] = f[13] = f[14] = f[15] = 0.f;
            }
#pragma unroll
            for (int kx = 0; kx < 5; ++kx) {
                float wv = sdw[c * 25 + ky * 5 + kx];
#pragma unroll
                for (int px = 0; px < 8; ++px) d[px] += wv * f[px + kx + 2];
            }
        }
#pragma unroll
        for (int oc = 0; oc < 8; ++oc) {
            float wm = spw[oc * 8 + c];
#pragma unroll
            for (int px = 0; px < 8; ++px) acc[oc][px] += wm * d[px];
        }
    }

#pragma unroll
    for (int oc = 0; oc < 8; ++oc) {
        union { bf16 h[8]; uint4 v; } pk;
#pragma unroll
        for (int px = 0; px < 8; ++px) pk.h[px] = f2b(acc[oc][px]);
        *(uint4*)(dw + ((size_t)b * QKV_CH + g * 8 + oc) * HW + y * 64 + x0) = pk.v;
    }
}

// K4a: kv partial accumulation. grid (NPG=2, 64, B); 8 positions/thread.
__global__ __launch_bounds__(256) void k_kv(const bf16* __restrict__ qkv,
                                            const bf16* __restrict__ agg,
                                            float* __restrict__ part) {
    int tid = threadIdx.x;
    int lane = tid & 63, wv = tid >> 6;
    int pg = blockIdx.x, h = blockIdx.y, b = blockIdx.z;
    int cbase = 24 * h;
    const bf16* src = (h < 32)
        ? qkv + ((size_t)b * QKV_CH + cbase) * HW
        : agg + ((size_t)b * QKV_CH + (cbase - QKV_CH)) * HW;
    int p0 = pg * 2048 + tid * 4;

    float acc[72];
#pragma unroll
    for (int i = 0; i < 72; ++i) acc[i] = 0.f;

#pragma unroll
    for (int ch = 0; ch < 2; ++ch) {
        int p = p0 + ch * 1024;
        float kf[8][4], vf[8][4];
#pragma unroll
        for (int d = 0; d < 8; ++d) {
            ushort4 u = *(const ushort4*)(src + (size_t)(8 + d) * HW + p);
            kf[d][0] = fmaxf(u2f(u.x), 0.f);
            kf[d][1] = fmaxf(u2f(u.y), 0.f);
            kf[d][2] = fmaxf(u2f(u.z), 0.f);
            kf[d][3] = fmaxf(u2f(u.w), 0.f);
        }
#pragma unroll
        for (int e = 0; e < 8; ++e) {
            ushort4 u = *(const ushort4*)(src + (size_t)(16 + e) * HW + p);
            vf[e][0] = u2f(u.x); vf[e][1] = u2f(u.y);
            vf[e][2] = u2f(u.z); vf[e][3] = u2f(u.w);
        }
#pragma unroll
        for (int j = 0; j < 4; ++j) {
#pragma unroll
            for (int d = 0; d < 8; ++d) {
#pragma unroll
                for (int e = 0; e < 8; ++e) acc[d * 9 + e] += kf[d][j] * vf[e][j];
                acc[d * 9 + 8] += kf[d][j];
            }
        }
    }

#pragma unroll
    for (int m = 1; m < 64; m <<= 1) {
#pragma unroll
        for (int i = 0; i < 72; ++i) acc[i] += __shfl_xor(acc[i], m, 64);
    }

    float t0 = 0.f, t1 = 0.f;
#pragma unroll
    for (int i = 0; i < 64; ++i) t0 = (lane == i) ? acc[i] : t0;
#pragma unroll
    for (int i = 0; i < 8; ++i) t1 = (lane == i) ? acc[64 + i] : t1;

    int bh = b * 64 + h;
    float* pp = part + ((size_t)(bh * NPG + pg) * 4 + wv) * 72;
    pp[lane] = t0;
    if (lane < 8) pp[64 + lane] = t1;
}

// K4b: apply. grid (2, 64, B); 8 positions/thread in 2 chunks.
__global__ __launch_bounds__(256) void k_apply(const bf16* __restrict__ qkv,
                                               const bf16* __restrict__ agg,
                                               const float* __restrict__ part,
                                               float* __restrict__ out) {
    int tid = threadIdx.x;
    int pg = blockIdx.x, h = blockIdx.y, b = blockIdx.z;
    int bh = b * 64 + h;

    __shared__ float skv[72];
    if (tid < 72) {
        const float* pp = part + (size_t)bh * (NPG * 4) * 72 + tid;
        float s = 0.f;
#pragma unroll
        for (int j = 0; j < NPG * 4; ++j) s += pp[(size_t)j * 72];
        skv[tid] = s;
    }
    __syncthreads();

    int cbase = 24 * h;
    const bf16* src = (h < 32)
        ? qkv + ((size_t)b * QKV_CH + cbase) * HW
        : agg + ((size_t)b * QKV_CH + (cbase - QKV_CH)) * HW;
    int p0 = pg * 2048 + tid * 4;

#pragma unroll
    for (int ch = 0; ch < 2; ++ch) {
        int p = p0 + ch * 1024;
        float qf[8][4];
#pragma unroll
        for (int d = 0; d < 8; ++d) {
            ushort4 u = *(const ushort4*)(src + (size_t)d * HW + p);
            qf[d][0] = fmaxf(u2f(u.x), 0.f);
            qf[d][1] = fmaxf(u2f(u.y), 0.f);
            qf[d][2] = fmaxf(u2f(u.z), 0.f);
            qf[d][3] = fmaxf(u2f(u.w), 0.f);
        }

        float num[9][4];
#pragma unroll
        for (int e = 0; e < 9; ++e) {
#pragma unroll
            for (int j = 0; j < 4; ++j) {
                float s = 0.f;
#pragma unroll
                for (int d = 0; d < 8; ++d) s += qf[d][j] * skv[d * 9 + e];
                num[e][j] = s;
            }
        }
        float iv[4];
#pragma unroll
        for (int j = 0; j < 4; ++j) iv[j] = 1.f / (num[8][j] + 1e-15f);

#pragma unroll
        for (int e = 0; e < 8; ++e) {
            float4 r;
            r.x = num[e][0] * iv[0];
            r.y = num[e][1] * iv[1];
            r.z = num[e][2] * iv[2];
            r.w = num[e][3] * iv[3];
            *(float4*)(out + ((size_t)b * PROJ_IN + h * 8 + e) * HW + p) = r;
        }
    }
}

// K5s: proj conv1x1 (256x512) + BN -> fp32, SCALAR-WEIGHT form (r18 verified).
// r19 change: unroll 4 -> 8 (same MLP-window rationale as k_qkv).
__global__ __launch_bounds__(256) void k_proj_s(const float* __restrict__ attn,
                                                const float* __restrict__ wT2,
                                                const float* __restrict__ gamma,
                                                const float* __restrict__ beta,
                                                const float* __restrict__ mean,
                                                const float* __restrict__ var,
                                                float* __restrict__ out) {
    int tid = threadIdx.x;
    int tp = tid & 63;
    int pg = blockIdx.x, og = blockIdx.y, b = blockIdx.z;

    int wuni = __builtin_amdgcn_readfirstlane(og * 32 + (tid >> 6) * 8);
    const float* wb = wT2 + wuni;

    float acc[8][4];
#pragma unroll
    for (int j = 0; j < 8; ++j)
#pragma unroll
        for (int i = 0; i < 4; ++i) acc[j][i] = 0.f;

    const float* ap = attn + (size_t)b * PROJ_IN * HW + pg * 256 + tp * 4;

#pragma unroll 8
    for (int c = 0; c < 512; ++c) {
        float4 xv = *(const float4*)(ap + (size_t)c * HW);
        const float* wr = wb + (size_t)c * PROJ_OUT;
        float4 w0 = *(const float4*)(wr);
        float4 w1 = *(const float4*)(wr + 4);
        float xs[4] = {xv.x, xv.y, xv.z, xv.w};
        float ws[8] = {w0.x, w0.y, w0.z, w0.w, w1.x, w1.y, w1.z, w1.w};
#pragma unroll
        for (int j = 0; j < 8; ++j)
#pragma unroll
            for (int i = 0; i < 4; ++i) acc[j][i] += ws[j] * xs[i];
    }

    int o0 = og * 32 + (tid >> 6) * 8;
#pragma unroll
    for (int j = 0; j < 8; ++j) {
        int o = o0 + j;
        float inv = gamma[o] * rsqrtf(var[o] + 1e-5f);
        float add = beta[o] - mean[o] * inv;
        float4 r;
        r.x = acc[j][0] * inv + add;
        r.y = acc[j][1] * inv + add;
        r.z = acc[j][2] * inv + add;
        r.w = acc[j][3] * inv + add;
        *(float4*)(out + ((size_t)b * PROJ_OUT + o) * HW + pg * 256 + tp * 4) = r;
    }
}

// K5: verified LDS fallback (used only when workspace can't hold wT2).
__global__ __launch_bounds__(256) void k_proj(const float* __restrict__ attn,
                                              const float* __restrict__ w,
                                              const float* __restrict__ gamma,
                                              const float* __restrict__ beta,
                                              const float* __restrict__ mean,
                                              const float* __restrict__ var,
                                              float* __restrict__ out) {
    int tid = threadIdx.x;
    int to = tid >> 6, tp = tid & 63;
    int pg = blockIdx.x, og = blockIdx.y, b = blockIdx.z;

    __shared__ float sw[256 * 36];

    float acc[8][4];
#pragma unroll
    for (int j = 0; j < 8; ++j)
#pragma unroll
        for (int i = 0; i < 4; ++i) acc[j][i] = 0.f;

    const float* ap = attn + (size_t)b * PROJ_IN * HW + pg * 256 + tp * 4;

    for (int h = 0; h < 2; ++h) {
        __syncthreads();
        for (int i = tid; i < 32 * 256; i += 256) {
            int o = i >> 8, c = i & 255;
            sw[c * 36 + o] = w[(size_t)(og * 32 + o) * 512 + h * 256 + c];
        }
        __syncthreads();
#pragma unroll 4
        for (int c = 0; c < 256; ++c) {
            float4 xv = *(const float4*)(ap + (size_t)(h * 256 + c) * HW);
            const float* wr = &sw[c * 36 + to * 8];
            float4 w0 = *(const float4*)(wr);
            float4 w1 = *(const float4*)(wr + 4);
            float xs[4] = {xv.x, xv.y, xv.z, xv.w};
            float ws[8] = {w0.x, w0.y, w0.z, w0.w, w1.x, w1.y, w1.z, w1.w};
#pragma unroll
            for (int j = 0; j < 8; ++j)
#pragma unroll
                for (int i = 0; i < 4; ++i) acc[j][i] += ws[j] * xs[i];
        }
    }

#pragma unroll
    for (int j = 0; j < 8; ++j) {
        int o = og * 32 + to * 8 + j;
        float inv = gamma[o] * rsqrtf(var[o] + 1e-5f);
        float add = beta[o] - mean[o] * inv;
        float4 r;
        r.x = acc[j][0] * inv + add;
        r.y = acc[j][1] * inv + add;
        r.z = acc[j][2] * inv + add;
        r.w = acc[j][3] * inv + add;
        *(float4*)(out + ((size_t)b * PROJ_OUT + o) * HW + pg * 256 + tp * 4) = r;
    }
}

extern "C" void kernel_launch(void* const* d_in, const int* in_sizes, int n_in,
                              void* d_out, int out_size, void* d_ws, size_t ws_size,
                              hipStream_t stream) {
    const float* x      = (const float*)d_in[0];
    const float* w_qkv  = (const float*)d_in[1];
    const float* w_dw   = (const float*)d_in[2];
    const float* w_pw   = (const float*)d_in[3];
    const float* w_proj = (const float*)d_in[4];
    const float* bn_g   = (const float*)d_in[5];
    const float* bn_b   = (const float*)d_in[6];
    const float* bn_m   = (const float*)d_in[7];
    const float* bn_v   = (const float*)d_in[8];
    float* out = (float*)d_out;

    char* ws = (char*)d_ws;
    bf16*  qkv  = (bf16*)(ws);                           // 48 MB
    bf16*  dwb  = (bf16*)(ws + (size_t)50331648);        // 48 MB
    float* attn = (float*)(ws + (size_t)100663296);      // 64 MB
    const size_t kMainWs = 167772160;                    // 160 MB
    const size_t kWtSz   = (size_t)QKV_CH * CIN * sizeof(float);        // 768 KB
    const size_t kWt2Sz  = (size_t)PROJ_IN * PROJ_OUT * sizeof(float);  // 512 KB
    const size_t kPartSz = (size_t)(B * 64) * NPG * 4 * 72 * sizeof(float);

    dim3 blk(256);
    bool fit = (ws_size >= kMainWs + kWtSz + kWt2Sz + kPartSz);
    float *wT, *wT2, *part;
    if (fit) {
        wT   = (float*)(ws + kMainWs);
        wT2  = (float*)(ws + kMainWs + kWtSz);
        part = (float*)(ws + kMainWs + kWtSz + kWt2Sz);
    } else {
        // d_out scratch: consumed before k_proj's write (same-stream order).
        wT   = (float*)d_out;
        wT2  = nullptr;                                   // LDS fallback
        part = (float*)((char*)d_out + 4194304);
    }

    k_wt   <<<dim3(3, 256), blk, 0, stream>>>(w_qkv, wT);
    if (fit) k_wt2<<<dim3(1, 512), blk, 0, stream>>>(w_proj, wT2);
    k_qkv  <<<dim3(8, 24, B), blk, 0, stream>>>(x, wT, qkv);
    k_dwagg<<<dim3(2, 96, B), blk, 0, stream>>>(qkv, w_dw, w_pw, dwb);
    k_kv   <<<dim3(NPG, 64, B), blk, 0, stream>>>(qkv, dwb, part);
    k_apply<<<dim3(2, 64, B), blk, 0, stream>>>(qkv, dwb, part, attn);
    if (fit)
        k_proj_s<<<dim3(16, 8, B), blk, 0, stream>>>(attn, wT2, bn_g, bn_b, bn_m, bn_v, out);
    else
        k_proj  <<<dim3(16, 8, B), blk, 0, stream>>>(attn, w_proj, bn_g, bn_b, bn_m, bn_v, out);
}

// Round 20
// 432.077 us; speedup vs baseline: 1.0849x; 1.0849x over previous
//
#include <hip/hip_runtime.h>
#include <hip/hip_bf16.h>

using bf16 = __hip_bfloat16;

__device__ __forceinline__ float b2f(bf16 v) { return __bfloat162float(v); }
__device__ __forceinline__ bf16 f2b(float f) { return __float2bfloat16(f); }
__device__ __forceinline__ float u2f(unsigned short u) {
    return __uint_as_float(((unsigned)u) << 16);
}
// unpack a 32-bit word holding two bf16 (little-endian) to two floats
__device__ __forceinline__ void unpk(unsigned int w, float& a, float& b) {
    a = __uint_as_float(w << 16);
    b = __uint_as_float(w & 0xffff0000u);
}

#define B 8
#define CIN 256
#define HW 4096
#define QKV_CH 768
#define PROJ_IN 512
#define PROJ_OUT 256
#define NPG 2

// K0a: transpose w_qkv (768x256) -> wT (256x768). grid (3, 256).
__global__ __launch_bounds__(256) void k_wt(const float* __restrict__ w,
                                            float* __restrict__ wT) {
    int o = blockIdx.x * 256 + threadIdx.x;
    int c = blockIdx.y;
    wT[(size_t)c * QKV_CH + o] = w[(size_t)o * CIN + c];
}

// K0b: transpose w_proj (256x512) -> wT2 (512x256). grid (1, 512).
__global__ __launch_bounds__(256) void k_wt2(const float* __restrict__ w,
                                             float* __restrict__ wT2) {
    int o = threadIdx.x;
    int c = blockIdx.y;
    wT2[(size_t)c * PROJ_OUT + o] = w[(size_t)o * PROJ_IN + c];
}

// K1: qkv = w_qkv(768x256) @ x(b,256,4096) -> bf16, SCALAR-WEIGHT form.
// ROUND-18 VERIFIED (session best 438.4us; k_qkv ~160us, LDS=0, VGPR 40,
// Occ 44%). block 256 = 2 o-groups x 128 p-threads; micro 16o x 4p;
// weights via wave-uniform s_load from wT; unroll 4.
// Falsified levers on this kernel (do NOT reapply): r12 chunked staging,
// r13 manual prefetch, r14 512-thread blocks, r19 unroll-8 (L2 thrash,
// FETCH 24.5->27.5MB, Occ 44->37%).
__global__ __launch_bounds__(256) void k_qkv(const float* __restrict__ x,
                                             const float* __restrict__ wT,
                                             bf16* __restrict__ qkv) {
    int tid = threadIdx.x;
    int tp = tid & 127;
    int pg = blockIdx.x, og = blockIdx.y, b = blockIdx.z;

    int wuni = __builtin_amdgcn_readfirstlane(og * 32 + (tid >> 7) * 16);
    const float* wb = wT + wuni;

    float acc[16][4];
#pragma unroll
    for (int j = 0; j < 16; ++j)
#pragma unroll
        for (int i = 0; i < 4; ++i) acc[j][i] = 0.f;

    const float* xp = x + (size_t)b * CIN * HW + pg * 512 + tp * 4;
#pragma unroll 4
    for (int c = 0; c < 256; ++c) {
        float4 xv = *(const float4*)(xp + (size_t)c * HW);
        const float* wr = wb + (size_t)c * QKV_CH;
        float4 w0 = *(const float4*)(wr);
        float4 w1 = *(const float4*)(wr + 4);
        float4 w2 = *(const float4*)(wr + 8);
        float4 w3 = *(const float4*)(wr + 12);
        float xs[4] = {xv.x, xv.y, xv.z, xv.w};
        float ws[16] = {w0.x, w0.y, w0.z, w0.w, w1.x, w1.y, w1.z, w1.w,
                        w2.x, w2.y, w2.z, w2.w, w3.x, w3.y, w3.z, w3.w};
#pragma unroll
        for (int j = 0; j < 16; ++j)
#pragma unroll
            for (int i = 0; i < 4; ++i) acc[j][i] += ws[j] * xs[i];
    }

    int o0 = og * 32 + (tid >> 7) * 16;
#pragma unroll
    for (int j = 0; j < 16; ++j) {
        int o = o0 + j;
        union { bf16 h[4]; uint2 v; } pk;
#pragma unroll
        for (int i = 0; i < 4; ++i) pk.h[i] = f2b(acc[j][i]);
        *(uint2*)(qkv + ((size_t)b * QKV_CH + o) * HW + pg * 512 + tp * 4) = pk.v;
    }
}

// K2+K3 fused: depthwise 5x5 (pad 2) + group 8->8 pointwise mix. grid (2, 96, B)
__global__ __launch_bounds__(256) void k_dwagg(const bf16* __restrict__ qkv,
                                               const float* __restrict__ wdw,
                                               const float* __restrict__ wpw,
                                               bf16* __restrict__ dw) {
    int tid = threadIdx.x;
    int g = blockIdx.y, b = blockIdx.z;
    int x0 = (tid & 7) * 8;
    int y  = blockIdx.x * 32 + (tid >> 3);

    __shared__ float sdw[200];
    __shared__ float spw[64];
    if (tid < 200) sdw[tid] = wdw[(size_t)g * 200 + tid];
    if (tid < 64)  spw[tid] = wpw[(size_t)g * 64 + tid];
    __syncthreads();

    const bf16* src0 = qkv + ((size_t)b * QKV_CH + g * 8) * HW;

    float acc[8][8];
#pragma unroll
    for (int oc = 0; oc < 8; ++oc)
#pragma unroll
        for (int px = 0; px < 8; ++px) acc[oc][px] = 0.f;

#pragma unroll
    for (int c = 0; c < 8; ++c) {
        const bf16* src = src0 + (size_t)c * HW;
        float d[8];
#pragma unroll
        for (int px = 0; px < 8; ++px) d[px] = 0.f;

#pragma unroll
        for (int ky = 0; ky < 5; ++ky) {
            int yy = y + ky - 2;
            if (yy < 0 || yy > 63) continue;
            const bf16* row = src + yy * 64;
            float f[16];
            if (x0 > 0) {
                uint2 u = *(const uint2*)(row + x0 - 4);
                unpk(u.x, f[0], f[1]); unpk(u.y, f[2], f[3]);
            } else {
                f[0] = f[1] = f[2] = f[3] = 0.f;
            }
            uint4 m = *(const uint4*)(row + x0);
            unpk(m.x, f[4], f[5]);  unpk(m.y, f[6], f[7]);
            unpk(m.z, f[8], f[9]);  unpk(m.w, f[10], f[11]);
            if (x0 < 56) {
                uint2 u = *(const uint2*)(row + x0 + 8);
                unpk(u.x, f[12], f[13]); unpk(u.y, f[14], f[15]);
            } else {
                f[12] = f[13] = f[14] = f[15] = 0.f;
            }
#pragma unroll
            for (int kx = 0; kx < 5; ++kx) {
                float wv = sdw[c * 25 + ky * 5 + kx];
#pragma unroll
                for (int px = 0; px < 8; ++px) d[px] += wv * f[px + kx + 2];
            }
        }
#pragma unroll
        for (int oc = 0; oc < 8; ++oc) {
            float wm = spw[oc * 8 + c];
#pragma unroll
            for (int px = 0; px < 8; ++px) acc[oc][px] += wm * d[px];
        }
    }

#pragma unroll
    for (int oc = 0; oc < 8; ++oc) {
        union { bf16 h[8]; uint4 v; } pk;
#pragma unroll
        for (int px = 0; px < 8; ++px) pk.h[px] = f2b(acc[oc][px]);
        *(uint4*)(dw + ((size_t)b * QKV_CH + g * 8 + oc) * HW + y * 64 + x0) = pk.v;
    }
}

// K4a: kv partial accumulation. grid (NPG=2, 64, B); 8 positions/thread.
__global__ __launch_bounds__(256) void k_kv(const bf16* __restrict__ qkv,
                                            const bf16* __restrict__ agg,
                                            float* __restrict__ part) {
    int tid = threadIdx.x;
    int lane = tid & 63, wv = tid >> 6;
    int pg = blockIdx.x, h = blockIdx.y, b = blockIdx.z;
    int cbase = 24 * h;
    const bf16* src = (h < 32)
        ? qkv + ((size_t)b * QKV_CH + cbase) * HW
        : agg + ((size_t)b * QKV_CH + (cbase - QKV_CH)) * HW;
    int p0 = pg * 2048 + tid * 4;

    float acc[72];
#pragma unroll
    for (int i = 0; i < 72; ++i) acc[i] = 0.f;

#pragma unroll
    for (int ch = 0; ch < 2; ++ch) {
        int p = p0 + ch * 1024;
        float kf[8][4], vf[8][4];
#pragma unroll
        for (int d = 0; d < 8; ++d) {
            ushort4 u = *(const ushort4*)(src + (size_t)(8 + d) * HW + p);
            kf[d][0] = fmaxf(u2f(u.x), 0.f);
            kf[d][1] = fmaxf(u2f(u.y), 0.f);
            kf[d][2] = fmaxf(u2f(u.z), 0.f);
            kf[d][3] = fmaxf(u2f(u.w), 0.f);
        }
#pragma unroll
        for (int e = 0; e < 8; ++e) {
            ushort4 u = *(const ushort4*)(src + (size_t)(16 + e) * HW + p);
            vf[e][0] = u2f(u.x); vf[e][1] = u2f(u.y);
            vf[e][2] = u2f(u.z); vf[e][3] = u2f(u.w);
        }
#pragma unroll
        for (int j = 0; j < 4; ++j) {
#pragma unroll
            for (int d = 0; d < 8; ++d) {
#pragma unroll
                for (int e = 0; e < 8; ++e) acc[d * 9 + e] += kf[d][j] * vf[e][j];
                acc[d * 9 + 8] += kf[d][j];
            }
        }
    }

#pragma unroll
    for (int m = 1; m < 64; m <<= 1) {
#pragma unroll
        for (int i = 0; i < 72; ++i) acc[i] += __shfl_xor(acc[i], m, 64);
    }

    float t0 = 0.f, t1 = 0.f;
#pragma unroll
    for (int i = 0; i < 64; ++i) t0 = (lane == i) ? acc[i] : t0;
#pragma unroll
    for (int i = 0; i < 8; ++i) t1 = (lane == i) ? acc[64 + i] : t1;

    int bh = b * 64 + h;
    float* pp = part + ((size_t)(bh * NPG + pg) * 4 + wv) * 72;
    pp[lane] = t0;
    if (lane < 8) pp[64 + lane] = t1;
}

// K4b: apply. grid (2, 64, B); 8 positions/thread in 2 chunks.
__global__ __launch_bounds__(256) void k_apply(const bf16* __restrict__ qkv,
                                               const bf16* __restrict__ agg,
                                               const float* __restrict__ part,
                                               float* __restrict__ out) {
    int tid = threadIdx.x;
    int pg = blockIdx.x, h = blockIdx.y, b = blockIdx.z;
    int bh = b * 64 + h;

    __shared__ float skv[72];
    if (tid < 72) {
        const float* pp = part + (size_t)bh * (NPG * 4) * 72 + tid;
        float s = 0.f;
#pragma unroll
        for (int j = 0; j < NPG * 4; ++j) s += pp[(size_t)j * 72];
        skv[tid] = s;
    }
    __syncthreads();

    int cbase = 24 * h;
    const bf16* src = (h < 32)
        ? qkv + ((size_t)b * QKV_CH + cbase) * HW
        : agg + ((size_t)b * QKV_CH + (cbase - QKV_CH)) * HW;
    int p0 = pg * 2048 + tid * 4;

#pragma unroll
    for (int ch = 0; ch < 2; ++ch) {
        int p = p0 + ch * 1024;
        float qf[8][4];
#pragma unroll
        for (int d = 0; d < 8; ++d) {
            ushort4 u = *(const ushort4*)(src + (size_t)d * HW + p);
            qf[d][0] = fmaxf(u2f(u.x), 0.f);
            qf[d][1] = fmaxf(u2f(u.y), 0.f);
            qf[d][2] = fmaxf(u2f(u.z), 0.f);
            qf[d][3] = fmaxf(u2f(u.w), 0.f);
        }

        float num[9][4];
#pragma unroll
        for (int e = 0; e < 9; ++e) {
#pragma unroll
            for (int j = 0; j < 4; ++j) {
                float s = 0.f;
#pragma unroll
                for (int d = 0; d < 8; ++d) s += qf[d][j] * skv[d * 9 + e];
                num[e][j] = s;
            }
        }
        float iv[4];
#pragma unroll
        for (int j = 0; j < 4; ++j) iv[j] = 1.f / (num[8][j] + 1e-15f);

#pragma unroll
        for (int e = 0; e < 8; ++e) {
            float4 r;
            r.x = num[e][0] * iv[0];
            r.y = num[e][1] * iv[1];
            r.z = num[e][2] * iv[2];
            r.w = num[e][3] * iv[3];
            *(float4*)(out + ((size_t)b * PROJ_IN + h * 8 + e) * HW + p) = r;
        }
    }
}

// K5s: proj conv1x1 (256x512) + BN -> fp32, SCALAR-WEIGHT form (r18 verified).
__global__ __launch_bounds__(256) void k_proj_s(const float* __restrict__ attn,
                                                const float* __restrict__ wT2,
                                                const float* __restrict__ gamma,
                                                const float* __restrict__ beta,
                                                const float* __restrict__ mean,
                                                const float* __restrict__ var,
                                                float* __restrict__ out) {
    int tid = threadIdx.x;
    int tp = tid & 63;
    int pg = blockIdx.x, og = blockIdx.y, b = blockIdx.z;

    int wuni = __builtin_amdgcn_readfirstlane(og * 32 + (tid >> 6) * 8);
    const float* wb = wT2 + wuni;

    float acc[8][4];
#pragma unroll
    for (int j = 0; j < 8; ++j)
#pragma unroll
        for (int i = 0; i < 4; ++i) acc[j][i] = 0.f;

    const float* ap = attn + (size_t)b * PROJ_IN * HW + pg * 256 + tp * 4;

#pragma unroll 4
    for (int c = 0; c < 512; ++c) {
        float4 xv = *(const float4*)(ap + (size_t)c * HW);
        const float* wr = wb + (size_t)c * PROJ_OUT;
        float4 w0 = *(const float4*)(wr);
        float4 w1 = *(const float4*)(wr + 4);
        float xs[4] = {xv.x, xv.y, xv.z, xv.w};
        float ws[8] = {w0.x, w0.y, w0.z, w0.w, w1.x, w1.y, w1.z, w1.w};
#pragma unroll
        for (int j = 0; j < 8; ++j)
#pragma unroll
            for (int i = 0; i < 4; ++i) acc[j][i] += ws[j] * xs[i];
    }

    int o0 = og * 32 + (tid >> 6) * 8;
#pragma unroll
    for (int j = 0; j < 8; ++j) {
        int o = o0 + j;
        float inv = gamma[o] * rsqrtf(var[o] + 1e-5f);
        float add = beta[o] - mean[o] * inv;
        float4 r;
        r.x = acc[j][0] * inv + add;
        r.y = acc[j][1] * inv + add;
        r.z = acc[j][2] * inv + add;
        r.w = acc[j][3] * inv + add;
        *(float4*)(out + ((size_t)b * PROJ_OUT + o) * HW + pg * 256 + tp * 4) = r;
    }
}

// K5: verified LDS fallback (used only when workspace can't hold wT2).
__global__ __launch_bounds__(256) void k_proj(const float* __restrict__ attn,
                                              const float* __restrict__ w,
                                              const float* __restrict__ gamma,
                                              const float* __restrict__ beta,
                                              const float* __restrict__ mean,
                                              const float* __restrict__ var,
                                              float* __restrict__ out) {
    int tid = threadIdx.x;
    int to = tid >> 6, tp = tid & 63;
    int pg = blockIdx.x, og = blockIdx.y, b = blockIdx.z;

    __shared__ float sw[256 * 36];

    float acc[8][4];
#pragma unroll
    for (int j = 0; j < 8; ++j)
#pragma unroll
        for (int i = 0; i < 4; ++i) acc[j][i] = 0.f;

    const float* ap = attn + (size_t)b * PROJ_IN * HW + pg * 256 + tp * 4;

    for (int h = 0; h < 2; ++h) {
        __syncthreads();
        for (int i = tid; i < 32 * 256; i += 256) {
            int o = i >> 8, c = i & 255;
            sw[c * 36 + o] = w[(size_t)(og * 32 + o) * 512 + h * 256 + c];
        }
        __syncthreads();
#pragma unroll 4
        for (int c = 0; c < 256; ++c) {
            float4 xv = *(const float4*)(ap + (size_t)(h * 256 + c) * HW);
            const float* wr = &sw[c * 36 + to * 8];
            float4 w0 = *(const float4*)(wr);
            float4 w1 = *(const float4*)(wr + 4);
            float xs[4] = {xv.x, xv.y, xv.z, xv.w};
            float ws[8] = {w0.x, w0.y, w0.z, w0.w, w1.x, w1.y, w1.z, w1.w};
#pragma unroll
            for (int j = 0; j < 8; ++j)
#pragma unroll
                for (int i = 0; i < 4; ++i) acc[j][i] += ws[j] * xs[i];
        }
    }

#pragma unroll
    for (int j = 0; j < 8; ++j) {
        int o = og * 32 + to * 8 + j;
        float inv = gamma[o] * rsqrtf(var[o] + 1e-5f);
        float add = beta[o] - mean[o] * inv;
        float4 r;
        r.x = acc[j][0] * inv + add;
        r.y = acc[j][1] * inv + add;
        r.z = acc[j][2] * inv + add;
        r.w = acc[j][3] * inv + add;
        *(float4*)(out + ((size_t)b * PROJ_OUT + o) * HW + pg * 256 + tp * 4) = r;
    }
}

extern "C" void kernel_launch(void* const* d_in, const int* in_sizes, int n_in,
                              void* d_out, int out_size, void* d_ws, size_t ws_size,
                              hipStream_t stream) {
    const float* x      = (const float*)d_in[0];
    const float* w_qkv  = (const float*)d_in[1];
    const float* w_dw   = (const float*)d_in[2];
    const float* w_pw   = (const float*)d_in[3];
    const float* w_proj = (const float*)d_in[4];
    const float* bn_g   = (const float*)d_in[5];
    const float* bn_b   = (const float*)d_in[6];
    const float* bn_m   = (const float*)d_in[7];
    const float* bn_v   = (const float*)d_in[8];
    float* out = (float*)d_out;

    char* ws = (char*)d_ws;
    bf16*  qkv  = (bf16*)(ws);                           // 48 MB
    bf16*  dwb  = (bf16*)(ws + (size_t)50331648);        // 48 MB
    float* attn = (float*)(ws + (size_t)100663296);      // 64 MB
    const size_t kMainWs = 167772160;                    // 160 MB
    const size_t kWtSz   = (size_t)QKV_CH * CIN * sizeof(float);        // 768 KB
    const size_t kWt2Sz  = (size_t)PROJ_IN * PROJ_OUT * sizeof(float);  // 512 KB
    const size_t kPartSz = (size_t)(B * 64) * NPG * 4 * 72 * sizeof(float);

    dim3 blk(256);
    bool fit = (ws_size >= kMainWs + kWtSz + kWt2Sz + kPartSz);
    float *wT, *wT2, *part;
    if (fit) {
        wT   = (float*)(ws + kMainWs);
        wT2  = (float*)(ws + kMainWs + kWtSz);
        part = (float*)(ws + kMainWs + kWtSz + kWt2Sz);
    } else {
        // d_out scratch: consumed before k_proj's write (same-stream order).
        wT   = (float*)d_out;
        wT2  = nullptr;                                   // LDS fallback
        part = (float*)((char*)d_out + 4194304);
    }

    k_wt   <<<dim3(3, 256), blk, 0, stream>>>(w_qkv, wT);
    if (fit) k_wt2<<<dim3(1, 512), blk, 0, stream>>>(w_proj, wT2);
    k_qkv  <<<dim3(8, 24, B), blk, 0, stream>>>(x, wT, qkv);
    k_dwagg<<<dim3(2, 96, B), blk, 0, stream>>>(qkv, w_dw, w_pw, dwb);
    k_kv   <<<dim3(NPG, 64, B), blk, 0, stream>>>(qkv, dwb, part);
    k_apply<<<dim3(2, 64, B), blk, 0, stream>>>(qkv, dwb, part, attn);
    if (fit)
        k_proj_s<<<dim3(16, 8, B), blk, 0, stream>>>(attn, wT2, bn_g, bn_b, bn_m, bn_v, out);
    else
        k_proj  <<<dim3(16, 8, B), blk, 0, stream>>>(attn, w_proj, bn_g, bn_b, bn_m, bn_v, out);
}